// Round 15
// baseline (381.493 us; speedup 1.0000x reference)
//
#include <hip/hip_runtime.h>

typedef __attribute__((ext_vector_type(8))) short short8;
typedef __attribute__((ext_vector_type(4))) float f32x4;

#define N_NODES 100000
#define N_EDGES 800000
#define NEG 0.2f
#define BN_EPS 1e-5f
#define AGG_GRID 2048
#define MG_GRID 1024
#define MG_TILES 3125
#define SC_CHUNKS 256

__device__ __forceinline__ ushort bf16b(float f) {
  unsigned u = __float_as_uint(f);
  return (ushort)((u + 0x7FFFu + ((u >> 16) & 1u)) >> 16);
}
__device__ __forceinline__ float bflo(unsigned u) { return __uint_as_float(u << 16); }
__device__ __forceinline__ float bfhi(unsigned u) { return __uint_as_float(u & 0xFFFF0000u); }

// ---------------- CSR build (dst-sorted edge list) ----------------
__global__ void k_hist(const int* __restrict__ dst, int* __restrict__ cnt,
                       unsigned* __restrict__ ctr, int e) {
  if (blockIdx.x == 0 && threadIdx.x < 2) ctr[threadIdx.x] = 0;  // init bnred counter
  int i = blockIdx.x * blockDim.x + threadIdx.x;
  if (i < e) atomicAdd(&cnt[dst[i]], 1);
}

__global__ void k_scan1(const int* __restrict__ cnt, int* __restrict__ rowptr,
                        int* __restrict__ bsums, int n) {
  __shared__ int sm[256];
  int i = blockIdx.x * 256 + threadIdx.x;
  int v = (i < n) ? cnt[i] : 0;
  sm[threadIdx.x] = v;
  __syncthreads();
  for (int off = 1; off < 256; off <<= 1) {
    int t = (threadIdx.x >= off) ? sm[threadIdx.x - off] : 0;
    __syncthreads();
    sm[threadIdx.x] += t;
    __syncthreads();
  }
  if (i < n) rowptr[i + 1] = sm[threadIdx.x];
  if (threadIdx.x == 255) bsums[blockIdx.x] = sm[255];
}

__global__ void k_scan2(int* __restrict__ bsums, int nb) {
  __shared__ int sm[512];
  int v = (threadIdx.x < nb) ? bsums[threadIdx.x] : 0;
  sm[threadIdx.x] = v;
  __syncthreads();
  for (int off = 1; off < 512; off <<= 1) {
    int t = (threadIdx.x >= off) ? sm[threadIdx.x - off] : 0;
    __syncthreads();
    sm[threadIdx.x] += t;
    __syncthreads();
  }
  if (threadIdx.x < nb) bsums[threadIdx.x] = sm[threadIdx.x] - v;  // exclusive
}

__global__ void k_scan3(int* __restrict__ rowptr, const int* __restrict__ bsums,
                        int* __restrict__ cursor, int n) {
  int i = blockIdx.x * 256 + threadIdx.x;
  if (i < n) {
    int val = rowptr[i + 1] + bsums[blockIdx.x];
    rowptr[i + 1] = val;
    if (i + 1 < n) cursor[i + 1] = val;
  }
  if (i == 0) { rowptr[0] = 0; cursor[0] = 0; }
}

// XCD-partitioned scatter: block b owns dst range (b&7) -> single-L2 line ownership
__global__ __launch_bounds__(256) void k_scatter(
    const int* __restrict__ src, const int* __restrict__ dst,
    int* __restrict__ cursor, int2* __restrict__ esort, int e) {
  int xcd = blockIdx.x & 7;
  int chunk = blockIdx.x >> 3;
  int lo = xcd * (N_NODES / 8);
  int hi = lo + (N_NODES / 8);
  int per = (e + SC_CHUNKS - 1) / SC_CHUNKS;
  int beg = chunk * per;
  int end = min(e, beg + per);
  for (int i = beg + threadIdx.x; i < end; i += 256) {
    int d = dst[i];
    if (d >= lo && d < hi) {
      int pos = atomicAdd(&cursor[d], 1);
      esort[pos] = make_int2(src[i], d);
    }
  }
}

// ---- pack 4 weight matrices (blocks 0..31) + W_pred (blocks 32..35) to frag order
__global__ void k_packW(const float* __restrict__ W_enc, const float* __restrict__ Ws,
                        const float* __restrict__ Wpred, ushort* __restrict__ Wp,
                        ushort* __restrict__ Wpp) {
  int s = blockIdx.x * 256 + threadIdx.x;
  if (s < 8192) {
    int wi = s >> 11, s2 = s & 2047;
    int kt = s2 >> 9, nb8 = (s2 >> 6) & 7, l = s2 & 63;
    const float* Wsrc = (wi == 0) ? W_enc : Ws + (size_t)(wi - 1) * 16384;
    int n = nb8 * 16 + (l & 15);
    int k0 = kt * 32 + (l >> 4) * 8;
    unsigned pk[4];
#pragma unroll
    for (int j = 0; j < 4; ++j) {
      ushort lo = bf16b(Wsrc[(size_t)(k0 + 2 * j) * 128 + n]);
      ushort hi = bf16b(Wsrc[(size_t)(k0 + 2 * j + 1) * 128 + n]);
      pk[j] = (unsigned)lo | ((unsigned)hi << 16);
    }
    *(uint4*)&Wp[(size_t)s * 8] = make_uint4(pk[0], pk[1], pk[2], pk[3]);
  } else {
    int s2 = s - 8192;  // 1024 slots for W_pred padded to 64 cols
    int kt = s2 >> 8, nb = (s2 >> 6) & 3, l = s2 & 63;
    int n = nb * 16 + (l & 15);
    int k0 = kt * 32 + (l >> 4) * 8;
    unsigned pk[4];
#pragma unroll
    for (int j = 0; j < 4; ++j) {
      float lo = (n < 40) ? Wpred[(size_t)(k0 + 2 * j) * 40 + n] : 0.f;
      float hi = (n < 40) ? Wpred[(size_t)(k0 + 2 * j + 1) * 40 + n] : 0.f;
      pk[j] = (unsigned)bf16b(lo) | ((unsigned)bf16b(hi) << 16);
    }
    *(uint4*)&Wpp[(size_t)s2 * 8] = make_uint4(pk[0], pk[1], pk[2], pk[3]);
  }
}

// ---------- FUSED encoder+layer0: hf = relu(feat@Wenc+b) @ W0, el/er + blockmax ---
__global__ __launch_bounds__(256) void k_fused(
    const float* __restrict__ feat, const ushort* __restrict__ WpE,
    const ushort* __restrict__ Wp0, const float* __restrict__ b_enc,
    const float* __restrict__ al, const float* __restrict__ ar,
    float* __restrict__ el, float* __restrict__ er,
    float4* __restrict__ blockmax, ushort* __restrict__ Cb) {
  __shared__ __align__(16) ushort Al[32 * 128];
  __shared__ __align__(16) ushort A2[32 * 128];
  int tid = threadIdx.x;
  int lane = tid & 63, w = tid >> 6;
  int wr = w & 1, wc = w >> 1;
  int l15 = lane & 15, l4 = lane >> 4;

  const uint4* wpE4 = (const uint4*)WpE;
  const uint4* wp04 = (const uint4*)Wp0;
  short8 bfrE[4][4], bfr0[4][4];
#pragma unroll
  for (int kt = 0; kt < 4; ++kt) {
#pragma unroll
    for (int nb = 0; nb < 4; ++nb) {
      uint4 tE = wpE4[(size_t)((kt * 8 + wc * 4 + nb) * 64 + lane)];
      bfrE[kt][nb] = *(short8*)&tE;
      uint4 t0 = wp04[(size_t)((kt * 8 + wc * 4 + nb) * 64 + lane)];
      bfr0[kt][nb] = *(short8*)&t0;
    }
  }

  float bv0 = b_enc[64 * wc + l15],      bv1 = b_enc[64 * wc + 16 + l15];
  float bv2 = b_enc[64 * wc + 32 + l15], bv3 = b_enc[64 * wc + 48 + l15];
  float alv0 = al[64 * wc + l15],      arv0 = ar[64 * wc + l15];
  float alv1 = al[64 * wc + 16 + l15], arv1 = ar[64 * wc + 16 + l15];
  float alv2 = al[64 * wc + 32 + l15], arv2 = ar[64 * wc + 32 + l15];
  float alv3 = al[64 * wc + 48 + l15], arv3 = ar[64 * wc + 48 + l15];

  float gmx0 = -1e30f, gmx1 = -1e30f;
  int srow = tid >> 3;
  int c16 = (tid & 7) * 16;
  int kc0 = (tid & 7) * 2;
  int arow = 16 * wr + l15;
  const char* abase = (const char*)Al + arow * 256;
  const char* abase2 = (const char*)A2 + arow * 256;
  int sw = arow & 7;

  for (int tile = blockIdx.x; tile < MG_TILES; tile += MG_GRID) {
    int rb = tile * 32;
    __syncthreads();
    {
      char* base = (char*)Al + srow * 256;
      const float4* srcp = (const float4*)(feat + (size_t)(rb + srow) * 128 + c16);
      float4 f[4];
#pragma unroll
      for (int j = 0; j < 4; ++j) f[j] = srcp[j];
      unsigned pk[8];
#pragma unroll
      for (int j = 0; j < 4; ++j) {
        pk[2 * j] = (unsigned)bf16b(f[j].x) | ((unsigned)bf16b(f[j].y) << 16);
        pk[2 * j + 1] = (unsigned)bf16b(f[j].z) | ((unsigned)bf16b(f[j].w) << 16);
      }
      *(uint4*)(base + ((kc0 ^ (srow & 7)) << 4)) = make_uint4(pk[0], pk[1], pk[2], pk[3]);
      *(uint4*)(base + (((kc0 + 1) ^ (srow & 7)) << 4)) = make_uint4(pk[4], pk[5], pk[6], pk[7]);
    }
    __syncthreads();

    f32x4 acc[4];
#pragma unroll
    for (int nb = 0; nb < 4; ++nb) acc[nb] = (f32x4){0.f, 0.f, 0.f, 0.f};
#pragma unroll
    for (int kt = 0; kt < 4; ++kt) {
      short8 af = *(const short8*)(abase + (((kt * 4 + l4) ^ sw) << 4));
      acc[0] = __builtin_amdgcn_mfma_f32_16x16x32_bf16(af, bfrE[kt][0], acc[0], 0, 0, 0);
      acc[1] = __builtin_amdgcn_mfma_f32_16x16x32_bf16(af, bfrE[kt][1], acc[1], 0, 0, 0);
      acc[2] = __builtin_amdgcn_mfma_f32_16x16x32_bf16(af, bfrE[kt][2], acc[2], 0, 0, 0);
      acc[3] = __builtin_amdgcn_mfma_f32_16x16x32_bf16(af, bfrE[kt][3], acc[3], 0, 0, 0);
    }
    {
      int rl0 = 16 * wr + 4 * l4;
#pragma unroll
      for (int i = 0; i < 4; ++i) {
        int rl = rl0 + i;
        int sw2 = rl & 7;
        char* b2 = (char*)A2 + rl * 256;
#pragma unroll
        for (int nb = 0; nb < 4; ++nb) {
          int col = 64 * wc + 16 * nb + l15;
          float bv = (nb == 0) ? bv0 : (nb == 1) ? bv1 : (nb == 2) ? bv2 : bv3;
          float v = fmaxf(acc[nb][i] + bv, 0.f);
          int chunk = col >> 3;
          *(ushort*)(b2 + (((chunk ^ sw2) << 4) | ((col & 7) * 2))) = bf16b(v);
        }
      }
    }
    __syncthreads();

    f32x4 acc2[4];
#pragma unroll
    for (int nb = 0; nb < 4; ++nb) acc2[nb] = (f32x4){0.f, 0.f, 0.f, 0.f};
#pragma unroll
    for (int kt = 0; kt < 4; ++kt) {
      short8 af = *(const short8*)(abase2 + (((kt * 4 + l4) ^ sw) << 4));
      acc2[0] = __builtin_amdgcn_mfma_f32_16x16x32_bf16(af, bfr0[kt][0], acc2[0], 0, 0, 0);
      acc2[1] = __builtin_amdgcn_mfma_f32_16x16x32_bf16(af, bfr0[kt][1], acc2[1], 0, 0, 0);
      acc2[2] = __builtin_amdgcn_mfma_f32_16x16x32_bf16(af, bfr0[kt][2], acc2[2], 0, 0, 0);
      acc2[3] = __builtin_amdgcn_mfma_f32_16x16x32_bf16(af, bfr0[kt][3], acc2[3], 0, 0, 0);
    }

    int row0 = rb + 16 * wr + 4 * l4;
#pragma unroll
    for (int i = 0; i < 4; ++i) {
      int row = row0 + i;
      float pl0 = acc2[0][i] * alv0 + acc2[1][i] * alv1;
      float pr0 = acc2[0][i] * arv0 + acc2[1][i] * arv1;
      float pl1 = acc2[2][i] * alv2 + acc2[3][i] * alv3;
      float pr1 = acc2[2][i] * arv2 + acc2[3][i] * arv3;
#pragma unroll
      for (int o = 1; o < 16; o <<= 1) {
        pl0 += __shfl_xor(pl0, o); pr0 += __shfl_xor(pr0, o);
        pl1 += __shfl_xor(pl1, o); pr1 += __shfl_xor(pr1, o);
      }
      gmx0 = fmaxf(gmx0, pl0); gmx1 = fmaxf(gmx1, pl1);
      if (l15 == 0) {
        el[(size_t)row * 4 + 2 * wc] = pl0;     er[(size_t)row * 4 + 2 * wc] = pr0;
        el[(size_t)row * 4 + 2 * wc + 1] = pl1; er[(size_t)row * 4 + 2 * wc + 1] = pr1;
      }
      size_t rbase = (size_t)row * 128 + 64 * wc + l15;
      Cb[rbase] = bf16b(acc2[0][i]);
      Cb[rbase + 16] = bf16b(acc2[1][i]);
      Cb[rbase + 32] = bf16b(acc2[2][i]);
      Cb[rbase + 48] = bf16b(acc2[3][i]);
    }
  }

  gmx0 = fmaxf(gmx0, __shfl_xor(gmx0, 16)); gmx0 = fmaxf(gmx0, __shfl_xor(gmx0, 32));
  gmx1 = fmaxf(gmx1, __shfl_xor(gmx1, 16)); gmx1 = fmaxf(gmx1, __shfl_xor(gmx1, 32));
  __shared__ float lm[4][2];
  if (lane == 0) { lm[w][0] = gmx0; lm[w][1] = gmx1; }
  __syncthreads();
  if (tid == 0) {
    float4 bm;
    bm.x = fmaxf(lm[0][0], lm[1][0]);
    bm.y = fmaxf(lm[0][1], lm[1][1]);
    bm.z = fmaxf(lm[2][0], lm[3][0]);
    bm.w = fmaxf(lm[2][1], lm[3][1]);
    blockmax[blockIdx.x] = bm;
  }
}

// ---------------- MFMA GEMM (persistent) layers 1/2: A bf16 + BN dequant ---------
template <int MODE>
__global__ __launch_bounds__(256) void k_mgemm(
    const float* __restrict__ Af, const ushort* __restrict__ Ab,
    const ushort* __restrict__ Wp, const float* __restrict__ bias,
    const float* __restrict__ stats, const float* __restrict__ al,
    const float* __restrict__ ar, float* __restrict__ el, float* __restrict__ er,
    float4* __restrict__ blockmax, ushort* __restrict__ Cb) {
  __shared__ __align__(16) ushort Al[32 * 128];
  int tid = threadIdx.x;
  int lane = tid & 63, w = tid >> 6;
  int wr = w & 1, wc = w >> 1;
  int l15 = lane & 15, l4 = lane >> 4;

  const uint4* wp4 = (const uint4*)Wp;
  short8 bfr[4][4];
#pragma unroll
  for (int kt = 0; kt < 4; ++kt) {
#pragma unroll
    for (int nb = 0; nb < 4; ++nb) {
      uint4 t = wp4[(size_t)((kt * 8 + wc * 4 + nb) * 64 + lane)];
      bfr[kt][nb] = *(short8*)&t;
    }
  }

  float alv0 = al[64 * wc + l15],      arv0 = ar[64 * wc + l15];
  float alv1 = al[64 * wc + 16 + l15], arv1 = ar[64 * wc + 16 + l15];
  float alv2 = al[64 * wc + 32 + l15], arv2 = ar[64 * wc + 32 + l15];
  float alv3 = al[64 * wc + 48 + l15], arv3 = ar[64 * wc + 48 + l15];

  float gmx0 = -1e30f, gmx1 = -1e30f;
  int srow = tid >> 3;
  int c16 = (tid & 7) * 16;
  int kc0 = (tid & 7) * 2;
  int arow = 16 * wr + l15;
  const char* abase = (const char*)Al + arow * 256;
  int sw = arow & 7;

  for (int tile = blockIdx.x; tile < MG_TILES; tile += MG_GRID) {
    int rb = tile * 32;
    __syncthreads();
    {
      char* base = (char*)Al + srow * 256;
      const uint4* srcp = (const uint4*)(Ab + (size_t)(rb + srow) * 128 + c16);
      uint4 v0 = srcp[0], v1 = srcp[1];
      unsigned pk[8];
#pragma unroll
      for (int j = 0; j < 4; ++j) {
        unsigned wv = ((const unsigned*)&v0)[j];
        float2 sc = *(const float2*)&stats[c16 + 2 * j];
        float2 sh = *(const float2*)&stats[128 + c16 + 2 * j];
        float x0 = fmaxf(bflo(wv) * sc.x + sh.x, 0.f);
        float x1 = fmaxf(bfhi(wv) * sc.y + sh.y, 0.f);
        pk[j] = (unsigned)bf16b(x0) | ((unsigned)bf16b(x1) << 16);
      }
#pragma unroll
      for (int j = 0; j < 4; ++j) {
        unsigned wv = ((const unsigned*)&v1)[j];
        float2 sc = *(const float2*)&stats[c16 + 8 + 2 * j];
        float2 sh = *(const float2*)&stats[128 + c16 + 8 + 2 * j];
        float x0 = fmaxf(bflo(wv) * sc.x + sh.x, 0.f);
        float x1 = fmaxf(bfhi(wv) * sc.y + sh.y, 0.f);
        pk[4 + j] = (unsigned)bf16b(x0) | ((unsigned)bf16b(x1) << 16);
      }
      *(uint4*)(base + ((kc0 ^ (srow & 7)) << 4)) = make_uint4(pk[0], pk[1], pk[2], pk[3]);
      *(uint4*)(base + (((kc0 + 1) ^ (srow & 7)) << 4)) = make_uint4(pk[4], pk[5], pk[6], pk[7]);
    }
    __syncthreads();

    f32x4 acc[4];
#pragma unroll
    for (int nb = 0; nb < 4; ++nb) acc[nb] = (f32x4){0.f, 0.f, 0.f, 0.f};
#pragma unroll
    for (int kt = 0; kt < 4; ++kt) {
      short8 af = *(const short8*)(abase + (((kt * 4 + l4) ^ sw) << 4));
      acc[0] = __builtin_amdgcn_mfma_f32_16x16x32_bf16(af, bfr[kt][0], acc[0], 0, 0, 0);
      acc[1] = __builtin_amdgcn_mfma_f32_16x16x32_bf16(af, bfr[kt][1], acc[1], 0, 0, 0);
      acc[2] = __builtin_amdgcn_mfma_f32_16x16x32_bf16(af, bfr[kt][2], acc[2], 0, 0, 0);
      acc[3] = __builtin_amdgcn_mfma_f32_16x16x32_bf16(af, bfr[kt][3], acc[3], 0, 0, 0);
    }

    int row0 = rb + 16 * wr + 4 * l4;
#pragma unroll
    for (int i = 0; i < 4; ++i) {
      int row = row0 + i;
      float pl0 = acc[0][i] * alv0 + acc[1][i] * alv1;
      float pr0 = acc[0][i] * arv0 + acc[1][i] * arv1;
      float pl1 = acc[2][i] * alv2 + acc[3][i] * alv3;
      float pr1 = acc[2][i] * arv2 + acc[3][i] * arv3;
#pragma unroll
      for (int o = 1; o < 16; o <<= 1) {
        pl0 += __shfl_xor(pl0, o); pr0 += __shfl_xor(pr0, o);
        pl1 += __shfl_xor(pl1, o); pr1 += __shfl_xor(pr1, o);
      }
      gmx0 = fmaxf(gmx0, pl0); gmx1 = fmaxf(gmx1, pl1);
      if (l15 == 0) {
        el[(size_t)row * 4 + 2 * wc] = pl0;     er[(size_t)row * 4 + 2 * wc] = pr0;
        el[(size_t)row * 4 + 2 * wc + 1] = pl1; er[(size_t)row * 4 + 2 * wc + 1] = pr1;
      }
      size_t rbase = (size_t)row * 128 + 64 * wc + l15;
      Cb[rbase] = bf16b(acc[0][i]);
      Cb[rbase + 16] = bf16b(acc[1][i]);
      Cb[rbase + 32] = bf16b(acc[2][i]);
      Cb[rbase + 48] = bf16b(acc[3][i]);
    }
  }

  gmx0 = fmaxf(gmx0, __shfl_xor(gmx0, 16)); gmx0 = fmaxf(gmx0, __shfl_xor(gmx0, 32));
  gmx1 = fmaxf(gmx1, __shfl_xor(gmx1, 16)); gmx1 = fmaxf(gmx1, __shfl_xor(gmx1, 32));
  __shared__ float lm[4][2];
  if (lane == 0) { lm[w][0] = gmx0; lm[w][1] = gmx1; }
  __syncthreads();
  if (tid == 0) {
    float4 bm;
    bm.x = fmaxf(lm[0][0], lm[1][0]);
    bm.y = fmaxf(lm[0][1], lm[1][1]);
    bm.z = fmaxf(lm[2][0], lm[3][0]);
    bm.w = fmaxf(lm[2][1], lm[3][1]);
    blockmax[blockIdx.x] = bm;
  }
}

// ---------------- reduce blockmax[MG_GRID] -> elmax[4] ----------------
__global__ __launch_bounds__(256) void k_elmax2(const float4* __restrict__ bm,
                                                float* __restrict__ elmax, int g) {
  float4 m = make_float4(-1e30f, -1e30f, -1e30f, -1e30f);
  for (int i = threadIdx.x; i < g; i += 256) {
    float4 v = bm[i];
    m.x = fmaxf(m.x, v.x); m.y = fmaxf(m.y, v.y);
    m.z = fmaxf(m.z, v.z); m.w = fmaxf(m.w, v.w);
  }
  __shared__ float4 sm[256];
  sm[threadIdx.x] = m;
  __syncthreads();
  for (int off = 128; off; off >>= 1) {
    if (threadIdx.x < off) {
      float4 o = sm[threadIdx.x + off];
      sm[threadIdx.x].x = fmaxf(sm[threadIdx.x].x, o.x);
      sm[threadIdx.x].y = fmaxf(sm[threadIdx.x].y, o.y);
      sm[threadIdx.x].z = fmaxf(sm[threadIdx.x].z, o.z);
      sm[threadIdx.x].w = fmaxf(sm[threadIdx.x].w, o.w);
    }
    __syncthreads();
  }
  if (threadIdx.x == 0) {
    elmax[0] = sm[0].x; elmax[1] = sm[0].y;
    elmax[2] = sm[0].z; elmax[3] = sm[0].w;
  }
}

// ---------------- per-edge softmax weights (one exp per edge-head) ----------------
__global__ __launch_bounds__(256) void k_edgew(
    const int2* __restrict__ esort, const float* __restrict__ el,
    const float* __restrict__ er, const float* __restrict__ elmax,
    float4* __restrict__ wgt, int e) {
  int j = blockIdx.x * 256 + threadIdx.x;
  if (j >= e) return;
  int2 sd = esort[j];
  float4 elv = *(const float4*)&el[(size_t)4 * sd.x];
  float4 erv = *(const float4*)&er[(size_t)4 * sd.y];
  float m0 = elmax[0] + erv.x;
  float m1 = elmax[1] + erv.y;
  float m2 = elmax[2] + erv.z;
  float m3 = elmax[3] + erv.w;
  m0 = fmaxf(m0, NEG * m0); m1 = fmaxf(m1, NEG * m1);
  m2 = fmaxf(m2, NEG * m2); m3 = fmaxf(m3, NEG * m3);
  float e0 = elv.x + erv.x; e0 = fmaxf(e0, NEG * e0);
  float e1 = elv.y + erv.y; e1 = fmaxf(e1, NEG * e1);
  float e2 = elv.z + erv.z; e2 = fmaxf(e2, NEG * e2);
  float e3 = elv.w + erv.w; e3 = fmaxf(e3, NEG * e3);
  float4 wv;
  wv.x = __expf(e0 - m0); wv.y = __expf(e1 - m1);
  wv.z = __expf(e2 - m2); wv.w = __expf(e3 - m3);
  wgt[j] = wv;
}

// ------- aggregation + fused BN partials (grid-stride, 1 wave/node, 6 chains) ----
__global__ __launch_bounds__(256, 8) void k_aggregate(
    const ushort* __restrict__ hf, const float4* __restrict__ wgt,
    const int* __restrict__ rowptr, const int2* __restrict__ esort,
    const float* __restrict__ bias, ushort* __restrict__ hpre,
    float* __restrict__ part, int n, int addres) {
  int tid = threadIdx.x;
  int w = tid >> 6, lane = tid & 63;
  int h = lane >> 4;
  int c0 = 2 * lane;
  float2 bb = *(const float2*)&bias[c0];
  float sbn0 = 0.f, sbn1 = 0.f, qbn0 = 0.f, qbn1 = 0.f;
  for (int wid = blockIdx.x * 4 + w; wid < n; wid += AGG_GRID * 4) {
    int beg = rowptr[wid], end = rowptr[wid + 1];
    float s[6], a0[6], a1[6];
#pragma unroll
    for (int t = 0; t < 6; ++t) { s[t] = 0.f; a0[t] = 0.f; a1[t] = 0.f; }
    for (int j0 = beg; j0 < end; j0 += 6) {
      int idx[6];
      float wv[6];
      unsigned hv[6];
#pragma unroll
      for (int t = 0; t < 6; ++t) {
        int jt = j0 + t;
        int jc = (jt < end) ? jt : beg;   // clamp to a valid slot
        idx[t] = esort[jc].x;
        wv[t] = (jt < end) ? ((const float*)(wgt + jc))[h] : 0.f;
      }
#pragma unroll
      for (int t = 0; t < 6; ++t)
        hv[t] = *(const unsigned*)(hf + (size_t)idx[t] * 128 + c0);
#pragma unroll
      for (int t = 0; t < 6; ++t) {
        s[t] += wv[t];
        a0[t] += wv[t] * bflo(hv[t]);
        a1[t] += wv[t] * bfhi(hv[t]);
      }
    }
    float ss = ((s[0] + s[1]) + (s[2] + s[3])) + (s[4] + s[5]);
    float inv = (end > beg) ? 1.f / ss : 0.f;
    float av0 = (((a0[0] + a0[1]) + (a0[2] + a0[3])) + (a0[4] + a0[5])) * inv;
    float av1 = (((a1[0] + a1[1]) + (a1[2] + a1[3])) + (a1[4] + a1[5])) * inv;
    float r0 = 0.f, r1 = 0.f;
    if (addres) {
      unsigned rr = *(const unsigned*)(hpre + (size_t)wid * 128 + c0);
      r0 = bflo(rr); r1 = bfhi(rr);
    }
    float o0 = av0 + bb.x + r0, o1 = av1 + bb.y + r1;
    *(unsigned*)(hpre + (size_t)wid * 128 + c0) =
        (unsigned)bf16b(o0) | ((unsigned)bf16b(o1) << 16);
    sbn0 += o0; qbn0 += o0 * o0;
    sbn1 += o1; qbn1 += o1 * o1;
  }
  __shared__ float red_s[4][128];
  __shared__ float red_q[4][128];
  red_s[w][c0] = sbn0; red_s[w][c0 + 1] = sbn1;
  red_q[w][c0] = qbn0; red_q[w][c0 + 1] = qbn1;
  __syncthreads();
  if (tid < 128)
    part[(size_t)blockIdx.x * 256 + tid] =
        (red_s[0][tid] + red_s[1][tid]) + (red_s[2][tid] + red_s[3][tid]);
  else if (tid < 256) {
    int c = tid - 128;
    part[(size_t)blockIdx.x * 256 + tid] =
        (red_q[0][c] + red_q[1][c]) + (red_q[2][c] + red_q[3][c]);
  }
}

// ------------- MFMA predictor: out = bnrelu(A_bf16) @ Wpred + bp (40 cols) -------
__global__ __launch_bounds__(256) void k_predm(
    const ushort* __restrict__ A, const float* __restrict__ stats,
    const ushort* __restrict__ Wp, const float* __restrict__ bias,
    float* __restrict__ out) {
  __shared__ __align__(16) ushort Al[32 * 128];
  int tid = threadIdx.x;
  int lane = tid & 63, w = tid >> 6;
  int wr = w & 1, wc = w >> 1;
  int l15 = lane & 15, l4 = lane >> 4;

  const uint4* wp4 = (const uint4*)Wp;
  short8 bfrP[4][2];
#pragma unroll
  for (int kt = 0; kt < 4; ++kt) {
#pragma unroll
    for (int n = 0; n < 2; ++n) {
      uint4 t = wp4[(size_t)((kt * 4 + wc * 2 + n) * 64 + lane)];
      bfrP[kt][n] = *(short8*)&t;
    }
  }
  int col0 = 32 * wc + l15, col1 = 32 * wc + 16 + l15;
  float bp0 = (col0 < 40) ? bias[col0] : 0.f;
  float bp1 = (col1 < 40) ? bias[col1] : 0.f;

  int srow = tid >> 3;
  int c16 = (tid & 7) * 16;
  int kc0 = (tid & 7) * 2;
  int arow = 16 * wr + l15;
  const char* abase = (const char*)Al + arow * 256;
  int sw = arow & 7;

  for (int tile = blockIdx.x; tile < MG_TILES; tile += MG_GRID) {
    int rb = tile * 32;
    __syncthreads();
    {
      char* base = (char*)Al + srow * 256;
      const uint4* srcp = (const uint4*)(A + (size_t)(rb + srow) * 128 + c16);
      uint4 v0 = srcp[0], v1 = srcp[1];
      unsigned pk[8];
#pragma unroll
      for (int j = 0; j < 4; ++j) {
        unsigned wv = ((const unsigned*)&v0)[j];
        float2 sc = *(const float2*)&stats[c16 + 2 * j];
        float2 sh = *(const float2*)&stats[128 + c16 + 2 * j];
        float x0 = fmaxf(bflo(wv) * sc.x + sh.x, 0.f);
        float x1 = fmaxf(bfhi(wv) * sc.y + sh.y, 0.f);
        pk[j] = (unsigned)bf16b(x0) | ((unsigned)bf16b(x1) << 16);
      }
#pragma unroll
      for (int j = 0; j < 4; ++j) {
        unsigned wv = ((const unsigned*)&v1)[j];
        float2 sc = *(const float2*)&stats[c16 + 8 + 2 * j];
        float2 sh = *(const float2*)&stats[128 + c16 + 8 + 2 * j];
        float x0 = fmaxf(bflo(wv) * sc.x + sh.x, 0.f);
        float x1 = fmaxf(bfhi(wv) * sc.y + sh.y, 0.f);
        pk[4 + j] = (unsigned)bf16b(x0) | ((unsigned)bf16b(x1) << 16);
      }
      *(uint4*)(base + ((kc0 ^ (srow & 7)) << 4)) = make_uint4(pk[0], pk[1], pk[2], pk[3]);
      *(uint4*)(base + (((kc0 + 1) ^ (srow & 7)) << 4)) = make_uint4(pk[4], pk[5], pk[6], pk[7]);
    }
    __syncthreads();

    f32x4 acc0 = (f32x4){0.f, 0.f, 0.f, 0.f};
    f32x4 acc1 = (f32x4){0.f, 0.f, 0.f, 0.f};
#pragma unroll
    for (int kt = 0; kt < 4; ++kt) {
      short8 af = *(const short8*)(abase + (((kt * 4 + l4) ^ sw) << 4));
      acc0 = __builtin_amdgcn_mfma_f32_16x16x32_bf16(af, bfrP[kt][0], acc0, 0, 0, 0);
      acc1 = __builtin_amdgcn_mfma_f32_16x16x32_bf16(af, bfrP[kt][1], acc1, 0, 0, 0);
    }

    int row0 = rb + 16 * wr + 4 * l4;
#pragma unroll
    for (int i = 0; i < 4; ++i) {
      int row = row0 + i;
      if (col0 < 40) out[(size_t)row * 40 + col0] = acc0[i] + bp0;
      if (col1 < 40) out[(size_t)row * 40 + col1] = acc1[i] + bp1;
    }
  }
}

// ---- column reduce + last-block BN finalize (tiny data before fence -> cheap) ----
__global__ __launch_bounds__(256) void k_bnred(
    const float* __restrict__ part, float* __restrict__ colsum,
    const float* __restrict__ gamma, const float* __restrict__ beta,
    float* __restrict__ stats, unsigned* __restrict__ ctr, int g, int n) {
  int v = blockIdx.x;
  float acc = 0.f;
  for (int b = threadIdx.x; b < g; b += 256) acc += part[(size_t)b * 256 + v];
  __shared__ float sm[256];
  sm[threadIdx.x] = acc;
  __syncthreads();
  for (int off = 128; off; off >>= 1) {
    if (threadIdx.x < off) sm[threadIdx.x] += sm[threadIdx.x + off];
    __syncthreads();
  }
  __shared__ int last;
  if (threadIdx.x == 0) {
    colsum[v] = sm[0];
    __threadfence();
    last = (atomicAdd(ctr, 1u) == (unsigned)(gridDim.x - 1));
  }
  __syncthreads();
  if (last) {
    __threadfence();
    if (threadIdx.x == 0) *ctr = 0;
    if (threadIdx.x < 128) {
      int c = threadIdx.x;
      float mean = colsum[c] / n;
      float var = colsum[128 + c] / n - mean * mean;
      float rstd = rsqrtf(var + BN_EPS);
      float scale = gamma[c] * rstd;
      stats[c] = scale;
      stats[128 + c] = beta[c] - mean * scale;
    }
  }
}

extern "C" void kernel_launch(void* const* d_in, const int* in_sizes, int n_in,
                              void* d_out, int out_size, void* d_ws, size_t ws_size,
                              hipStream_t stream) {
  const float* feat   = (const float*)d_in[0];
  const int*   src    = (const int*)d_in[1];
  const int*   dst    = (const int*)d_in[2];
  const float* W_enc  = (const float*)d_in[3];
  const float* b_enc  = (const float*)d_in[4];
  const float* Ws     = (const float*)d_in[5];
  const float* a_ls   = (const float*)d_in[6];
  const float* a_rs   = (const float*)d_in[7];
  const float* biases = (const float*)d_in[8];
  const float* gammas = (const float*)d_in[9];
  const float* betas  = (const float*)d_in[10];
  const float* W_pred = (const float*)d_in[11];
  const float* b_pred = (const float*)d_in[12];
  float* out = (float*)d_out;

  char* p = (char*)d_ws;
  auto alloc = [&](size_t bytes) {
    char* q = p;
    p += (bytes + 255) & ~(size_t)255;
    return q;
  };
  ushort* hf_bf = (ushort*)alloc((size_t)N_NODES * 128 * 2);
  ushort* hpre  = (ushort*)alloc((size_t)N_NODES * 128 * 2);
  float* el     = (float*)alloc((size_t)N_NODES * 4 * 4);
  float* er     = (float*)alloc((size_t)N_NODES * 4 * 4);
  float* part   = (float*)alloc((size_t)AGG_GRID * 256 * 4);
  float* colsum = (float*)alloc(256 * 4);
  float* stats  = (float*)alloc(256 * 4);
  ushort* Wpack = (ushort*)alloc((size_t)4 * 2048 * 16);
  ushort* Wppack= (ushort*)alloc((size_t)1024 * 16);
  float4* bmax  = (float4*)alloc((size_t)MG_GRID * 16);
  float* elmax  = (float*)alloc(4 * 4);
  unsigned* ctr = (unsigned*)alloc(256);
  int* rowptr   = (int*)alloc((size_t)(N_NODES + 1) * 4);
  int* cursor   = (int*)alloc((size_t)N_NODES * 4);
  int* bsums    = (int*)alloc(512 * 4);
  int2* esort   = (int2*)alloc((size_t)N_EDGES * 8);
  float4* wgt   = (float4*)alloc((size_t)N_EDGES * 16);

  // CSR build (dst-sorted)
  hipMemsetAsync(cursor, 0, (size_t)N_NODES * 4, stream);
  k_hist<<<(N_EDGES + 255) / 256, 256, 0, stream>>>(dst, cursor, ctr, N_EDGES);
  int nb = (N_NODES + 255) / 256;  // 391
  k_scan1<<<nb, 256, 0, stream>>>(cursor, rowptr, bsums, N_NODES);
  k_scan2<<<1, 512, 0, stream>>>(bsums, nb);
  k_scan3<<<nb, 256, 0, stream>>>(rowptr, bsums, cursor, N_NODES);
  k_scatter<<<SC_CHUNKS * 8, 256, 0, stream>>>(src, dst, cursor, esort, N_EDGES);

  // pack weights (4 layer matrices + predictor) to MFMA fragment order
  k_packW<<<36, 256, 0, stream>>>(W_enc, Ws, W_pred, Wpack, Wppack);

  for (int L = 0; L < 3; ++L) {
    const float* al = a_ls + L * 128;
    const float* ar = a_rs + L * 128;
    const ushort* wp = Wpack + (size_t)(1 + L) * 16384;
    if (L == 0)
      k_fused<<<MG_GRID, 256, 0, stream>>>(feat, Wpack, wp, b_enc, al, ar, el, er,
                                           bmax, hf_bf);
    else
      k_mgemm<2><<<MG_GRID, 256, 0, stream>>>(nullptr, hpre, wp, nullptr, stats, al,
                                              ar, el, er, bmax, hf_bf);
    k_elmax2<<<1, 256, 0, stream>>>(bmax, elmax, MG_GRID);
    k_edgew<<<(N_EDGES + 255) / 256, 256, 0, stream>>>(esort, el, er, elmax, wgt,
                                                       N_EDGES);
    k_aggregate<<<AGG_GRID, 256, 0, stream>>>(hf_bf, wgt, rowptr, esort,
                                              biases + L * 128, hpre, part, N_NODES,
                                              L > 0 ? 1 : 0);
    k_bnred<<<256, 256, 0, stream>>>(part, colsum, gammas + L * 128, betas + L * 128,
                                     stats, ctr, AGG_GRID, N_NODES);
  }
  // predictor uses layer-2 BN stats
  k_predm<<<MG_GRID, 256, 0, stream>>>(hpre, stats, Wppack, b_pred, out);
}

// Round 16
// 372.909 us; speedup vs baseline: 1.0230x; 1.0230x over previous
//
#include <hip/hip_runtime.h>

typedef __attribute__((ext_vector_type(8))) short short8;
typedef __attribute__((ext_vector_type(4))) float f32x4;

#define N_NODES 100000
#define N_EDGES 800000
#define NEG 0.2f
#define BN_EPS 1e-5f
#define AGG_GRID 2048
#define MG_GRID 1024
#define MG_TILES 3125
#define SC_CHUNKS 256

__device__ __forceinline__ ushort bf16b(float f) {
  unsigned u = __float_as_uint(f);
  return (ushort)((u + 0x7FFFu + ((u >> 16) & 1u)) >> 16);
}
__device__ __forceinline__ float bflo(unsigned u) { return __uint_as_float(u << 16); }
__device__ __forceinline__ float bfhi(unsigned u) { return __uint_as_float(u & 0xFFFF0000u); }

// ---------------- CSR build (dst-sorted edge list) ----------------
__global__ void k_hist(const int* __restrict__ dst, int* __restrict__ cnt,
                       unsigned* __restrict__ ctr, int e) {
  if (blockIdx.x == 0 && threadIdx.x < 2) ctr[threadIdx.x] = 0;  // init bnred counter
  int i = blockIdx.x * blockDim.x + threadIdx.x;
  if (i < e) atomicAdd(&cnt[dst[i]], 1);
}

__global__ void k_scan1(const int* __restrict__ cnt, int* __restrict__ rowptr,
                        int* __restrict__ bsums, int n) {
  __shared__ int sm[256];
  int i = blockIdx.x * 256 + threadIdx.x;
  int v = (i < n) ? cnt[i] : 0;
  sm[threadIdx.x] = v;
  __syncthreads();
  for (int off = 1; off < 256; off <<= 1) {
    int t = (threadIdx.x >= off) ? sm[threadIdx.x - off] : 0;
    __syncthreads();
    sm[threadIdx.x] += t;
    __syncthreads();
  }
  if (i < n) rowptr[i + 1] = sm[threadIdx.x];
  if (threadIdx.x == 255) bsums[blockIdx.x] = sm[255];
}

__global__ void k_scan2(int* __restrict__ bsums, int nb) {
  __shared__ int sm[512];
  int v = (threadIdx.x < nb) ? bsums[threadIdx.x] : 0;
  sm[threadIdx.x] = v;
  __syncthreads();
  for (int off = 1; off < 512; off <<= 1) {
    int t = (threadIdx.x >= off) ? sm[threadIdx.x - off] : 0;
    __syncthreads();
    sm[threadIdx.x] += t;
    __syncthreads();
  }
  if (threadIdx.x < nb) bsums[threadIdx.x] = sm[threadIdx.x] - v;  // exclusive
}

__global__ void k_scan3(int* __restrict__ rowptr, const int* __restrict__ bsums,
                        int* __restrict__ cursor, int n) {
  int i = blockIdx.x * 256 + threadIdx.x;
  if (i < n) {
    int val = rowptr[i + 1] + bsums[blockIdx.x];
    rowptr[i + 1] = val;
    if (i + 1 < n) cursor[i + 1] = val;
  }
  if (i == 0) { rowptr[0] = 0; cursor[0] = 0; }
}

// XCD-partitioned scatter: block b owns dst range (b&7) -> single-L2 line ownership
__global__ __launch_bounds__(256) void k_scatter(
    const int* __restrict__ src, const int* __restrict__ dst,
    int* __restrict__ cursor, int2* __restrict__ esort, int e) {
  int xcd = blockIdx.x & 7;
  int chunk = blockIdx.x >> 3;
  int lo = xcd * (N_NODES / 8);
  int hi = lo + (N_NODES / 8);
  int per = (e + SC_CHUNKS - 1) / SC_CHUNKS;
  int beg = chunk * per;
  int end = min(e, beg + per);
  for (int i = beg + threadIdx.x; i < end; i += 256) {
    int d = dst[i];
    if (d >= lo && d < hi) {
      int pos = atomicAdd(&cursor[d], 1);
      esort[pos] = make_int2(src[i], d);
    }
  }
}

// ---- pack 4 weight matrices (blocks 0..31) + W_pred (blocks 32..35) to frag order
__global__ void k_packW(const float* __restrict__ W_enc, const float* __restrict__ Ws,
                        const float* __restrict__ Wpred, ushort* __restrict__ Wp,
                        ushort* __restrict__ Wpp) {
  int s = blockIdx.x * 256 + threadIdx.x;
  if (s < 8192) {
    int wi = s >> 11, s2 = s & 2047;
    int kt = s2 >> 9, nb8 = (s2 >> 6) & 7, l = s2 & 63;
    const float* Wsrc = (wi == 0) ? W_enc : Ws + (size_t)(wi - 1) * 16384;
    int n = nb8 * 16 + (l & 15);
    int k0 = kt * 32 + (l >> 4) * 8;
    unsigned pk[4];
#pragma unroll
    for (int j = 0; j < 4; ++j) {
      ushort lo = bf16b(Wsrc[(size_t)(k0 + 2 * j) * 128 + n]);
      ushort hi = bf16b(Wsrc[(size_t)(k0 + 2 * j + 1) * 128 + n]);
      pk[j] = (unsigned)lo | ((unsigned)hi << 16);
    }
    *(uint4*)&Wp[(size_t)s * 8] = make_uint4(pk[0], pk[1], pk[2], pk[3]);
  } else {
    int s2 = s - 8192;  // 1024 slots for W_pred padded to 64 cols
    int kt = s2 >> 8, nb = (s2 >> 6) & 3, l = s2 & 63;
    int n = nb * 16 + (l & 15);
    int k0 = kt * 32 + (l >> 4) * 8;
    unsigned pk[4];
#pragma unroll
    for (int j = 0; j < 4; ++j) {
      float lo = (n < 40) ? Wpred[(size_t)(k0 + 2 * j) * 40 + n] : 0.f;
      float hi = (n < 40) ? Wpred[(size_t)(k0 + 2 * j + 1) * 40 + n] : 0.f;
      pk[j] = (unsigned)bf16b(lo) | ((unsigned)bf16b(hi) << 16);
    }
    *(uint4*)&Wpp[(size_t)s2 * 8] = make_uint4(pk[0], pk[1], pk[2], pk[3]);
  }
}

// ---------- FUSED encoder+layer0: hf = relu(feat@Wenc+b) @ W0, el/er + blockmax ---
__global__ __launch_bounds__(256) void k_fused(
    const float* __restrict__ feat, const ushort* __restrict__ WpE,
    const ushort* __restrict__ Wp0, const float* __restrict__ b_enc,
    const float* __restrict__ al, const float* __restrict__ ar,
    float* __restrict__ el, float* __restrict__ er,
    float4* __restrict__ blockmax, ushort* __restrict__ Cb) {
  __shared__ __align__(16) ushort Al[32 * 128];
  __shared__ __align__(16) ushort A2[32 * 128];
  int tid = threadIdx.x;
  int lane = tid & 63, w = tid >> 6;
  int wr = w & 1, wc = w >> 1;
  int l15 = lane & 15, l4 = lane >> 4;

  const uint4* wpE4 = (const uint4*)WpE;
  const uint4* wp04 = (const uint4*)Wp0;
  short8 bfrE[4][4], bfr0[4][4];
#pragma unroll
  for (int kt = 0; kt < 4; ++kt) {
#pragma unroll
    for (int nb = 0; nb < 4; ++nb) {
      uint4 tE = wpE4[(size_t)((kt * 8 + wc * 4 + nb) * 64 + lane)];
      bfrE[kt][nb] = *(short8*)&tE;
      uint4 t0 = wp04[(size_t)((kt * 8 + wc * 4 + nb) * 64 + lane)];
      bfr0[kt][nb] = *(short8*)&t0;
    }
  }

  float bv0 = b_enc[64 * wc + l15],      bv1 = b_enc[64 * wc + 16 + l15];
  float bv2 = b_enc[64 * wc + 32 + l15], bv3 = b_enc[64 * wc + 48 + l15];
  float alv0 = al[64 * wc + l15],      arv0 = ar[64 * wc + l15];
  float alv1 = al[64 * wc + 16 + l15], arv1 = ar[64 * wc + 16 + l15];
  float alv2 = al[64 * wc + 32 + l15], arv2 = ar[64 * wc + 32 + l15];
  float alv3 = al[64 * wc + 48 + l15], arv3 = ar[64 * wc + 48 + l15];

  float gmx0 = -1e30f, gmx1 = -1e30f;
  int srow = tid >> 3;
  int c16 = (tid & 7) * 16;
  int kc0 = (tid & 7) * 2;
  int arow = 16 * wr + l15;
  const char* abase = (const char*)Al + arow * 256;
  const char* abase2 = (const char*)A2 + arow * 256;
  int sw = arow & 7;

  for (int tile = blockIdx.x; tile < MG_TILES; tile += MG_GRID) {
    int rb = tile * 32;
    __syncthreads();
    {
      char* base = (char*)Al + srow * 256;
      const float4* srcp = (const float4*)(feat + (size_t)(rb + srow) * 128 + c16);
      float4 f[4];
#pragma unroll
      for (int j = 0; j < 4; ++j) f[j] = srcp[j];
      unsigned pk[8];
#pragma unroll
      for (int j = 0; j < 4; ++j) {
        pk[2 * j] = (unsigned)bf16b(f[j].x) | ((unsigned)bf16b(f[j].y) << 16);
        pk[2 * j + 1] = (unsigned)bf16b(f[j].z) | ((unsigned)bf16b(f[j].w) << 16);
      }
      *(uint4*)(base + ((kc0 ^ (srow & 7)) << 4)) = make_uint4(pk[0], pk[1], pk[2], pk[3]);
      *(uint4*)(base + (((kc0 + 1) ^ (srow & 7)) << 4)) = make_uint4(pk[4], pk[5], pk[6], pk[7]);
    }
    __syncthreads();

    f32x4 acc[4];
#pragma unroll
    for (int nb = 0; nb < 4; ++nb) acc[nb] = (f32x4){0.f, 0.f, 0.f, 0.f};
#pragma unroll
    for (int kt = 0; kt < 4; ++kt) {
      short8 af = *(const short8*)(abase + (((kt * 4 + l4) ^ sw) << 4));
      acc[0] = __builtin_amdgcn_mfma_f32_16x16x32_bf16(af, bfrE[kt][0], acc[0], 0, 0, 0);
      acc[1] = __builtin_amdgcn_mfma_f32_16x16x32_bf16(af, bfrE[kt][1], acc[1], 0, 0, 0);
      acc[2] = __builtin_amdgcn_mfma_f32_16x16x32_bf16(af, bfrE[kt][2], acc[2], 0, 0, 0);
      acc[3] = __builtin_amdgcn_mfma_f32_16x16x32_bf16(af, bfrE[kt][3], acc[3], 0, 0, 0);
    }
    {
      int rl0 = 16 * wr + 4 * l4;
#pragma unroll
      for (int i = 0; i < 4; ++i) {
        int rl = rl0 + i;
        int sw2 = rl & 7;
        char* b2 = (char*)A2 + rl * 256;
#pragma unroll
        for (int nb = 0; nb < 4; ++nb) {
          int col = 64 * wc + 16 * nb + l15;
          float bv = (nb == 0) ? bv0 : (nb == 1) ? bv1 : (nb == 2) ? bv2 : bv3;
          float v = fmaxf(acc[nb][i] + bv, 0.f);
          int chunk = col >> 3;
          *(ushort*)(b2 + (((chunk ^ sw2) << 4) | ((col & 7) * 2))) = bf16b(v);
        }
      }
    }
    __syncthreads();

    f32x4 acc2[4];
#pragma unroll
    for (int nb = 0; nb < 4; ++nb) acc2[nb] = (f32x4){0.f, 0.f, 0.f, 0.f};
#pragma unroll
    for (int kt = 0; kt < 4; ++kt) {
      short8 af = *(const short8*)(abase2 + (((kt * 4 + l4) ^ sw) << 4));
      acc2[0] = __builtin_amdgcn_mfma_f32_16x16x32_bf16(af, bfr0[kt][0], acc2[0], 0, 0, 0);
      acc2[1] = __builtin_amdgcn_mfma_f32_16x16x32_bf16(af, bfr0[kt][1], acc2[1], 0, 0, 0);
      acc2[2] = __builtin_amdgcn_mfma_f32_16x16x32_bf16(af, bfr0[kt][2], acc2[2], 0, 0, 0);
      acc2[3] = __builtin_amdgcn_mfma_f32_16x16x32_bf16(af, bfr0[kt][3], acc2[3], 0, 0, 0);
    }

    int row0 = rb + 16 * wr + 4 * l4;
#pragma unroll
    for (int i = 0; i < 4; ++i) {
      int row = row0 + i;
      float pl0 = acc2[0][i] * alv0 + acc2[1][i] * alv1;
      float pr0 = acc2[0][i] * arv0 + acc2[1][i] * arv1;
      float pl1 = acc2[2][i] * alv2 + acc2[3][i] * alv3;
      float pr1 = acc2[2][i] * arv2 + acc2[3][i] * arv3;
#pragma unroll
      for (int o = 1; o < 16; o <<= 1) {
        pl0 += __shfl_xor(pl0, o); pr0 += __shfl_xor(pr0, o);
        pl1 += __shfl_xor(pl1, o); pr1 += __shfl_xor(pr1, o);
      }
      gmx0 = fmaxf(gmx0, pl0); gmx1 = fmaxf(gmx1, pl1);
      if (l15 == 0) {
        el[(size_t)row * 4 + 2 * wc] = pl0;     er[(size_t)row * 4 + 2 * wc] = pr0;
        el[(size_t)row * 4 + 2 * wc + 1] = pl1; er[(size_t)row * 4 + 2 * wc + 1] = pr1;
      }
      size_t rbase = (size_t)row * 128 + 64 * wc + l15;
      Cb[rbase] = bf16b(acc2[0][i]);
      Cb[rbase + 16] = bf16b(acc2[1][i]);
      Cb[rbase + 32] = bf16b(acc2[2][i]);
      Cb[rbase + 48] = bf16b(acc2[3][i]);
    }
  }

  gmx0 = fmaxf(gmx0, __shfl_xor(gmx0, 16)); gmx0 = fmaxf(gmx0, __shfl_xor(gmx0, 32));
  gmx1 = fmaxf(gmx1, __shfl_xor(gmx1, 16)); gmx1 = fmaxf(gmx1, __shfl_xor(gmx1, 32));
  __shared__ float lm[4][2];
  if (lane == 0) { lm[w][0] = gmx0; lm[w][1] = gmx1; }
  __syncthreads();
  if (tid == 0) {
    float4 bm;
    bm.x = fmaxf(lm[0][0], lm[1][0]);
    bm.y = fmaxf(lm[0][1], lm[1][1]);
    bm.z = fmaxf(lm[2][0], lm[3][0]);
    bm.w = fmaxf(lm[2][1], lm[3][1]);
    blockmax[blockIdx.x] = bm;
  }
}

// ---------------- MFMA GEMM (persistent) layers 1/2: A bf16 + BN dequant ---------
template <int MODE>
__global__ __launch_bounds__(256) void k_mgemm(
    const float* __restrict__ Af, const ushort* __restrict__ Ab,
    const ushort* __restrict__ Wp, const float* __restrict__ bias,
    const float* __restrict__ stats, const float* __restrict__ al,
    const float* __restrict__ ar, float* __restrict__ el, float* __restrict__ er,
    float4* __restrict__ blockmax, ushort* __restrict__ Cb) {
  __shared__ __align__(16) ushort Al[32 * 128];
  int tid = threadIdx.x;
  int lane = tid & 63, w = tid >> 6;
  int wr = w & 1, wc = w >> 1;
  int l15 = lane & 15, l4 = lane >> 4;

  const uint4* wp4 = (const uint4*)Wp;
  short8 bfr[4][4];
#pragma unroll
  for (int kt = 0; kt < 4; ++kt) {
#pragma unroll
    for (int nb = 0; nb < 4; ++nb) {
      uint4 t = wp4[(size_t)((kt * 8 + wc * 4 + nb) * 64 + lane)];
      bfr[kt][nb] = *(short8*)&t;
    }
  }

  float alv0 = al[64 * wc + l15],      arv0 = ar[64 * wc + l15];
  float alv1 = al[64 * wc + 16 + l15], arv1 = ar[64 * wc + 16 + l15];
  float alv2 = al[64 * wc + 32 + l15], arv2 = ar[64 * wc + 32 + l15];
  float alv3 = al[64 * wc + 48 + l15], arv3 = ar[64 * wc + 48 + l15];

  float gmx0 = -1e30f, gmx1 = -1e30f;
  int srow = tid >> 3;
  int c16 = (tid & 7) * 16;
  int kc0 = (tid & 7) * 2;
  int arow = 16 * wr + l15;
  const char* abase = (const char*)Al + arow * 256;
  int sw = arow & 7;

  for (int tile = blockIdx.x; tile < MG_TILES; tile += MG_GRID) {
    int rb = tile * 32;
    __syncthreads();
    {
      char* base = (char*)Al + srow * 256;
      const uint4* srcp = (const uint4*)(Ab + (size_t)(rb + srow) * 128 + c16);
      uint4 v0 = srcp[0], v1 = srcp[1];
      unsigned pk[8];
#pragma unroll
      for (int j = 0; j < 4; ++j) {
        unsigned wv = ((const unsigned*)&v0)[j];
        float2 sc = *(const float2*)&stats[c16 + 2 * j];
        float2 sh = *(const float2*)&stats[128 + c16 + 2 * j];
        float x0 = fmaxf(bflo(wv) * sc.x + sh.x, 0.f);
        float x1 = fmaxf(bfhi(wv) * sc.y + sh.y, 0.f);
        pk[j] = (unsigned)bf16b(x0) | ((unsigned)bf16b(x1) << 16);
      }
#pragma unroll
      for (int j = 0; j < 4; ++j) {
        unsigned wv = ((const unsigned*)&v1)[j];
        float2 sc = *(const float2*)&stats[c16 + 8 + 2 * j];
        float2 sh = *(const float2*)&stats[128 + c16 + 8 + 2 * j];
        float x0 = fmaxf(bflo(wv) * sc.x + sh.x, 0.f);
        float x1 = fmaxf(bfhi(wv) * sc.y + sh.y, 0.f);
        pk[4 + j] = (unsigned)bf16b(x0) | ((unsigned)bf16b(x1) << 16);
      }
      *(uint4*)(base + ((kc0 ^ (srow & 7)) << 4)) = make_uint4(pk[0], pk[1], pk[2], pk[3]);
      *(uint4*)(base + (((kc0 + 1) ^ (srow & 7)) << 4)) = make_uint4(pk[4], pk[5], pk[6], pk[7]);
    }
    __syncthreads();

    f32x4 acc[4];
#pragma unroll
    for (int nb = 0; nb < 4; ++nb) acc[nb] = (f32x4){0.f, 0.f, 0.f, 0.f};
#pragma unroll
    for (int kt = 0; kt < 4; ++kt) {
      short8 af = *(const short8*)(abase + (((kt * 4 + l4) ^ sw) << 4));
      acc[0] = __builtin_amdgcn_mfma_f32_16x16x32_bf16(af, bfr[kt][0], acc[0], 0, 0, 0);
      acc[1] = __builtin_amdgcn_mfma_f32_16x16x32_bf16(af, bfr[kt][1], acc[1], 0, 0, 0);
      acc[2] = __builtin_amdgcn_mfma_f32_16x16x32_bf16(af, bfr[kt][2], acc[2], 0, 0, 0);
      acc[3] = __builtin_amdgcn_mfma_f32_16x16x32_bf16(af, bfr[kt][3], acc[3], 0, 0, 0);
    }

    int row0 = rb + 16 * wr + 4 * l4;
#pragma unroll
    for (int i = 0; i < 4; ++i) {
      int row = row0 + i;
      float pl0 = acc[0][i] * alv0 + acc[1][i] * alv1;
      float pr0 = acc[0][i] * arv0 + acc[1][i] * arv1;
      float pl1 = acc[2][i] * alv2 + acc[3][i] * alv3;
      float pr1 = acc[2][i] * arv2 + acc[3][i] * arv3;
#pragma unroll
      for (int o = 1; o < 16; o <<= 1) {
        pl0 += __shfl_xor(pl0, o); pr0 += __shfl_xor(pr0, o);
        pl1 += __shfl_xor(pl1, o); pr1 += __shfl_xor(pr1, o);
      }
      gmx0 = fmaxf(gmx0, pl0); gmx1 = fmaxf(gmx1, pl1);
      if (l15 == 0) {
        el[(size_t)row * 4 + 2 * wc] = pl0;     er[(size_t)row * 4 + 2 * wc] = pr0;
        el[(size_t)row * 4 + 2 * wc + 1] = pl1; er[(size_t)row * 4 + 2 * wc + 1] = pr1;
      }
      size_t rbase = (size_t)row * 128 + 64 * wc + l15;
      Cb[rbase] = bf16b(acc[0][i]);
      Cb[rbase + 16] = bf16b(acc[1][i]);
      Cb[rbase + 32] = bf16b(acc[2][i]);
      Cb[rbase + 48] = bf16b(acc[3][i]);
    }
  }

  gmx0 = fmaxf(gmx0, __shfl_xor(gmx0, 16)); gmx0 = fmaxf(gmx0, __shfl_xor(gmx0, 32));
  gmx1 = fmaxf(gmx1, __shfl_xor(gmx1, 16)); gmx1 = fmaxf(gmx1, __shfl_xor(gmx1, 32));
  __shared__ float lm[4][2];
  if (lane == 0) { lm[w][0] = gmx0; lm[w][1] = gmx1; }
  __syncthreads();
  if (tid == 0) {
    float4 bm;
    bm.x = fmaxf(lm[0][0], lm[1][0]);
    bm.y = fmaxf(lm[0][1], lm[1][1]);
    bm.z = fmaxf(lm[2][0], lm[3][0]);
    bm.w = fmaxf(lm[2][1], lm[3][1]);
    blockmax[blockIdx.x] = bm;
  }
}

// ---------------- reduce blockmax[MG_GRID] -> elmax[4] ----------------
__global__ __launch_bounds__(256) void k_elmax2(const float4* __restrict__ bm,
                                                float* __restrict__ elmax, int g) {
  float4 m = make_float4(-1e30f, -1e30f, -1e30f, -1e30f);
  for (int i = threadIdx.x; i < g; i += 256) {
    float4 v = bm[i];
    m.x = fmaxf(m.x, v.x); m.y = fmaxf(m.y, v.y);
    m.z = fmaxf(m.z, v.z); m.w = fmaxf(m.w, v.w);
  }
  __shared__ float4 sm[256];
  sm[threadIdx.x] = m;
  __syncthreads();
  for (int off = 128; off; off >>= 1) {
    if (threadIdx.x < off) {
      float4 o = sm[threadIdx.x + off];
      sm[threadIdx.x].x = fmaxf(sm[threadIdx.x].x, o.x);
      sm[threadIdx.x].y = fmaxf(sm[threadIdx.x].y, o.y);
      sm[threadIdx.x].z = fmaxf(sm[threadIdx.x].z, o.z);
      sm[threadIdx.x].w = fmaxf(sm[threadIdx.x].w, o.w);
    }
    __syncthreads();
  }
  if (threadIdx.x == 0) {
    elmax[0] = sm[0].x; elmax[1] = sm[0].y;
    elmax[2] = sm[0].z; elmax[3] = sm[0].w;
  }
}

// ---------------- per-edge softmax weights (one exp per edge-head) ----------------
__global__ __launch_bounds__(256) void k_edgew(
    const int2* __restrict__ esort, const float* __restrict__ el,
    const float* __restrict__ er, const float* __restrict__ elmax,
    float4* __restrict__ wgt, int e) {
  int j = blockIdx.x * 256 + threadIdx.x;
  if (j >= e) return;
  int2 sd = esort[j];
  float4 elv = *(const float4*)&el[(size_t)4 * sd.x];
  float4 erv = *(const float4*)&er[(size_t)4 * sd.y];
  float m0 = elmax[0] + erv.x;
  float m1 = elmax[1] + erv.y;
  float m2 = elmax[2] + erv.z;
  float m3 = elmax[3] + erv.w;
  m0 = fmaxf(m0, NEG * m0); m1 = fmaxf(m1, NEG * m1);
  m2 = fmaxf(m2, NEG * m2); m3 = fmaxf(m3, NEG * m3);
  float e0 = elv.x + erv.x; e0 = fmaxf(e0, NEG * e0);
  float e1 = elv.y + erv.y; e1 = fmaxf(e1, NEG * e1);
  float e2 = elv.z + erv.z; e2 = fmaxf(e2, NEG * e2);
  float e3 = elv.w + erv.w; e3 = fmaxf(e3, NEG * e3);
  float4 wv;
  wv.x = __expf(e0 - m0); wv.y = __expf(e1 - m1);
  wv.z = __expf(e2 - m2); wv.w = __expf(e3 - m3);
  wgt[j] = wv;
}

// ------- aggregation + fused BN partials (grid-stride, 1 wave/node, 4 chains) ----
__global__ __launch_bounds__(256, 8) void k_aggregate(
    const ushort* __restrict__ hf, const float4* __restrict__ wgt,
    const int* __restrict__ rowptr, const int2* __restrict__ esort,
    const float* __restrict__ bias, ushort* __restrict__ hpre,
    float* __restrict__ part, int n, int addres) {
  int tid = threadIdx.x;
  int w = tid >> 6, lane = tid & 63;
  int h = lane >> 4;
  int c0 = 2 * lane;
  float2 bb = *(const float2*)&bias[c0];
  float sbn0 = 0.f, sbn1 = 0.f, qbn0 = 0.f, qbn1 = 0.f;
  for (int wid = blockIdx.x * 4 + w; wid < n; wid += AGG_GRID * 4) {
    int beg = rowptr[wid], end = rowptr[wid + 1];
    float s0 = 0.f, a00 = 0.f, a10 = 0.f;
    float s1 = 0.f, a01 = 0.f, a11 = 0.f;
    float s2 = 0.f, a02 = 0.f, a12 = 0.f;
    float s3 = 0.f, a03 = 0.f, a13 = 0.f;
    int j = beg;
    for (; j + 4 <= end; j += 4) {
      int sA = esort[j].x, sB = esort[j + 1].x, sC = esort[j + 2].x, sD = esort[j + 3].x;
      float wA = ((const float*)(wgt + j))[h];
      float wB = ((const float*)(wgt + j + 1))[h];
      float wC = ((const float*)(wgt + j + 2))[h];
      float wD = ((const float*)(wgt + j + 3))[h];
      unsigned hA = *(const unsigned*)(hf + (size_t)sA * 128 + c0);
      unsigned hB = *(const unsigned*)(hf + (size_t)sB * 128 + c0);
      unsigned hC = *(const unsigned*)(hf + (size_t)sC * 128 + c0);
      unsigned hD = *(const unsigned*)(hf + (size_t)sD * 128 + c0);
      s0 += wA; a00 += wA * bflo(hA); a10 += wA * bfhi(hA);
      s1 += wB; a01 += wB * bflo(hB); a11 += wB * bfhi(hB);
      s2 += wC; a02 += wC * bflo(hC); a12 += wC * bfhi(hC);
      s3 += wD; a03 += wD * bflo(hD); a13 += wD * bfhi(hD);
    }
    if (j < end) {  // predicated final quad (indices clamped, weights masked)
      int jB = (j + 1 < end) ? j + 1 : j;
      int jC = (j + 2 < end) ? j + 2 : j;
      int jD = (j + 3 < end) ? j + 3 : j;
      int sA = esort[j].x, sB = esort[jB].x, sC = esort[jC].x, sD = esort[jD].x;
      float wA = ((const float*)(wgt + j))[h];
      float wB = (j + 1 < end) ? ((const float*)(wgt + jB))[h] : 0.f;
      float wC = (j + 2 < end) ? ((const float*)(wgt + jC))[h] : 0.f;
      float wD = (j + 3 < end) ? ((const float*)(wgt + jD))[h] : 0.f;
      unsigned hA = *(const unsigned*)(hf + (size_t)sA * 128 + c0);
      unsigned hB = *(const unsigned*)(hf + (size_t)sB * 128 + c0);
      unsigned hC = *(const unsigned*)(hf + (size_t)sC * 128 + c0);
      unsigned hD = *(const unsigned*)(hf + (size_t)sD * 128 + c0);
      s0 += wA; a00 += wA * bflo(hA); a10 += wA * bfhi(hA);
      s1 += wB; a01 += wB * bflo(hB); a11 += wB * bfhi(hB);
      s2 += wC; a02 += wC * bflo(hC); a12 += wC * bfhi(hC);
      s3 += wD; a03 += wD * bflo(hD); a13 += wD * bfhi(hD);
    }
    float s = (s0 + s1) + (s2 + s3);
    float inv = (end > beg) ? 1.f / s : 0.f;
    float a0 = ((a00 + a01) + (a02 + a03)) * inv;
    float a1 = ((a10 + a11) + (a12 + a13)) * inv;
    float r0 = 0.f, r1 = 0.f;
    if (addres) {
      unsigned rr = *(const unsigned*)(hpre + (size_t)wid * 128 + c0);
      r0 = bflo(rr); r1 = bfhi(rr);
    }
    float o0 = a0 + bb.x + r0, o1 = a1 + bb.y + r1;
    *(unsigned*)(hpre + (size_t)wid * 128 + c0) =
        (unsigned)bf16b(o0) | ((unsigned)bf16b(o1) << 16);
    sbn0 += o0; qbn0 += o0 * o0;
    sbn1 += o1; qbn1 += o1 * o1;
  }
  __shared__ float red_s[4][128];
  __shared__ float red_q[4][128];
  red_s[w][c0] = sbn0; red_s[w][c0 + 1] = sbn1;
  red_q[w][c0] = qbn0; red_q[w][c0 + 1] = qbn1;
  __syncthreads();
  if (tid < 128)
    part[(size_t)blockIdx.x * 256 + tid] =
        (red_s[0][tid] + red_s[1][tid]) + (red_s[2][tid] + red_s[3][tid]);
  else if (tid < 256) {
    int c = tid - 128;
    part[(size_t)blockIdx.x * 256 + tid] =
        (red_q[0][c] + red_q[1][c]) + (red_q[2][c] + red_q[3][c]);
  }
}

// ------------- MFMA predictor: out = bnrelu(A_bf16) @ Wpred + bp (40 cols) -------
__global__ __launch_bounds__(256) void k_predm(
    const ushort* __restrict__ A, const float* __restrict__ stats,
    const ushort* __restrict__ Wp, const float* __restrict__ bias,
    float* __restrict__ out) {
  __shared__ __align__(16) ushort Al[32 * 128];
  int tid = threadIdx.x;
  int lane = tid & 63, w = tid >> 6;
  int wr = w & 1, wc = w >> 1;
  int l15 = lane & 15, l4 = lane >> 4;

  const uint4* wp4 = (const uint4*)Wp;
  short8 bfrP[4][2];
#pragma unroll
  for (int kt = 0; kt < 4; ++kt) {
#pragma unroll
    for (int n = 0; n < 2; ++n) {
      uint4 t = wp4[(size_t)((kt * 4 + wc * 2 + n) * 64 + lane)];
      bfrP[kt][n] = *(short8*)&t;
    }
  }
  int col0 = 32 * wc + l15, col1 = 32 * wc + 16 + l15;
  float bp0 = (col0 < 40) ? bias[col0] : 0.f;
  float bp1 = (col1 < 40) ? bias[col1] : 0.f;

  int srow = tid >> 3;
  int c16 = (tid & 7) * 16;
  int kc0 = (tid & 7) * 2;
  int arow = 16 * wr + l15;
  const char* abase = (const char*)Al + arow * 256;
  int sw = arow & 7;

  for (int tile = blockIdx.x; tile < MG_TILES; tile += MG_GRID) {
    int rb = tile * 32;
    __syncthreads();
    {
      char* base = (char*)Al + srow * 256;
      const uint4* srcp = (const uint4*)(A + (size_t)(rb + srow) * 128 + c16);
      uint4 v0 = srcp[0], v1 = srcp[1];
      unsigned pk[8];
#pragma unroll
      for (int j = 0; j < 4; ++j) {
        unsigned wv = ((const unsigned*)&v0)[j];
        float2 sc = *(const float2*)&stats[c16 + 2 * j];
        float2 sh = *(const float2*)&stats[128 + c16 + 2 * j];
        float x0 = fmaxf(bflo(wv) * sc.x + sh.x, 0.f);
        float x1 = fmaxf(bfhi(wv) * sc.y + sh.y, 0.f);
        pk[j] = (unsigned)bf16b(x0) | ((unsigned)bf16b(x1) << 16);
      }
#pragma unroll
      for (int j = 0; j < 4; ++j) {
        unsigned wv = ((const unsigned*)&v1)[j];
        float2 sc = *(const float2*)&stats[c16 + 8 + 2 * j];
        float2 sh = *(const float2*)&stats[128 + c16 + 8 + 2 * j];
        float x0 = fmaxf(bflo(wv) * sc.x + sh.x, 0.f);
        float x1 = fmaxf(bfhi(wv) * sc.y + sh.y, 0.f);
        pk[4 + j] = (unsigned)bf16b(x0) | ((unsigned)bf16b(x1) << 16);
      }
      *(uint4*)(base + ((kc0 ^ (srow & 7)) << 4)) = make_uint4(pk[0], pk[1], pk[2], pk[3]);
      *(uint4*)(base + (((kc0 + 1) ^ (srow & 7)) << 4)) = make_uint4(pk[4], pk[5], pk[6], pk[7]);
    }
    __syncthreads();

    f32x4 acc0 = (f32x4){0.f, 0.f, 0.f, 0.f};
    f32x4 acc1 = (f32x4){0.f, 0.f, 0.f, 0.f};
#pragma unroll
    for (int kt = 0; kt < 4; ++kt) {
      short8 af = *(const short8*)(abase + (((kt * 4 + l4) ^ sw) << 4));
      acc0 = __builtin_amdgcn_mfma_f32_16x16x32_bf16(af, bfrP[kt][0], acc0, 0, 0, 0);
      acc1 = __builtin_amdgcn_mfma_f32_16x16x32_bf16(af, bfrP[kt][1], acc1, 0, 0, 0);
    }

    int row0 = rb + 16 * wr + 4 * l4;
#pragma unroll
    for (int i = 0; i < 4; ++i) {
      int row = row0 + i;
      if (col0 < 40) out[(size_t)row * 40 + col0] = acc0[i] + bp0;
      if (col1 < 40) out[(size_t)row * 40 + col1] = acc1[i] + bp1;
    }
  }
}

// ---- column reduce + last-block BN finalize (tiny data before fence -> cheap) ----
__global__ __launch_bounds__(256) void k_bnred(
    const float* __restrict__ part, float* __restrict__ colsum,
    const float* __restrict__ gamma, const float* __restrict__ beta,
    float* __restrict__ stats, unsigned* __restrict__ ctr, int g, int n) {
  int v = blockIdx.x;
  float acc = 0.f;
  for (int b = threadIdx.x; b < g; b += 256) acc += part[(size_t)b * 256 + v];
  __shared__ float sm[256];
  sm[threadIdx.x] = acc;
  __syncthreads();
  for (int off = 128; off; off >>= 1) {
    if (threadIdx.x < off) sm[threadIdx.x] += sm[threadIdx.x + off];
    __syncthreads();
  }
  __shared__ int last;
  if (threadIdx.x == 0) {
    colsum[v] = sm[0];
    __threadfence();
    last = (atomicAdd(ctr, 1u) == (unsigned)(gridDim.x - 1));
  }
  __syncthreads();
  if (last) {
    __threadfence();
    if (threadIdx.x == 0) *ctr = 0;
    if (threadIdx.x < 128) {
      int c = threadIdx.x;
      float mean = colsum[c] / n;
      float var = colsum[128 + c] / n - mean * mean;
      float rstd = rsqrtf(var + BN_EPS);
      float scale = gamma[c] * rstd;
      stats[c] = scale;
      stats[128 + c] = beta[c] - mean * scale;
    }
  }
}

extern "C" void kernel_launch(void* const* d_in, const int* in_sizes, int n_in,
                              void* d_out, int out_size, void* d_ws, size_t ws_size,
                              hipStream_t stream) {
  const float* feat   = (const float*)d_in[0];
  const int*   src    = (const int*)d_in[1];
  const int*   dst    = (const int*)d_in[2];
  const float* W_enc  = (const float*)d_in[3];
  const float* b_enc  = (const float*)d_in[4];
  const float* Ws     = (const float*)d_in[5];
  const float* a_ls   = (const float*)d_in[6];
  const float* a_rs   = (const float*)d_in[7];
  const float* biases = (const float*)d_in[8];
  const float* gammas = (const float*)d_in[9];
  const float* betas  = (const float*)d_in[10];
  const float* W_pred = (const float*)d_in[11];
  const float* b_pred = (const float*)d_in[12];
  float* out = (float*)d_out;

  char* p = (char*)d_ws;
  auto alloc = [&](size_t bytes) {
    char* q = p;
    p += (bytes + 255) & ~(size_t)255;
    return q;
  };
  ushort* hf_bf = (ushort*)alloc((size_t)N_NODES * 128 * 2);
  ushort* hpre  = (ushort*)alloc((size_t)N_NODES * 128 * 2);
  float* el     = (float*)alloc((size_t)N_NODES * 4 * 4);
  float* er     = (float*)alloc((size_t)N_NODES * 4 * 4);
  float* part   = (float*)alloc((size_t)AGG_GRID * 256 * 4);
  float* colsum = (float*)alloc(256 * 4);
  float* stats  = (float*)alloc(256 * 4);
  ushort* Wpack = (ushort*)alloc((size_t)4 * 2048 * 16);
  ushort* Wppack= (ushort*)alloc((size_t)1024 * 16);
  float4* bmax  = (float4*)alloc((size_t)MG_GRID * 16);
  float* elmax  = (float*)alloc(4 * 4);
  unsigned* ctr = (unsigned*)alloc(256);
  int* rowptr   = (int*)alloc((size_t)(N_NODES + 1) * 4);
  int* cursor   = (int*)alloc((size_t)N_NODES * 4);
  int* bsums    = (int*)alloc(512 * 4);
  int2* esort   = (int2*)alloc((size_t)N_EDGES * 8);
  float4* wgt   = (float4*)alloc((size_t)N_EDGES * 16);

  // CSR build (dst-sorted)
  hipMemsetAsync(cursor, 0, (size_t)N_NODES * 4, stream);
  k_hist<<<(N_EDGES + 255) / 256, 256, 0, stream>>>(dst, cursor, ctr, N_EDGES);
  int nb = (N_NODES + 255) / 256;  // 391
  k_scan1<<<nb, 256, 0, stream>>>(cursor, rowptr, bsums, N_NODES);
  k_scan2<<<1, 512, 0, stream>>>(bsums, nb);
  k_scan3<<<nb, 256, 0, stream>>>(rowptr, bsums, cursor, N_NODES);
  k_scatter<<<SC_CHUNKS * 8, 256, 0, stream>>>(src, dst, cursor, esort, N_EDGES);

  // pack weights (4 layer matrices + predictor) to MFMA fragment order
  k_packW<<<36, 256, 0, stream>>>(W_enc, Ws, W_pred, Wpack, Wppack);

  for (int L = 0; L < 3; ++L) {
    const float* al = a_ls + L * 128;
    const float* ar = a_rs + L * 128;
    const ushort* wp = Wpack + (size_t)(1 + L) * 16384;
    if (L == 0)
      k_fused<<<MG_GRID, 256, 0, stream>>>(feat, Wpack, wp, b_enc, al, ar, el, er,
                                           bmax, hf_bf);
    else
      k_mgemm<2><<<MG_GRID, 256, 0, stream>>>(nullptr, hpre, wp, nullptr, stats, al,
                                              ar, el, er, bmax, hf_bf);
    k_elmax2<<<1, 256, 0, stream>>>(bmax, elmax, MG_GRID);
    k_edgew<<<(N_EDGES + 255) / 256, 256, 0, stream>>>(esort, el, er, elmax, wgt,
                                                       N_EDGES);
    k_aggregate<<<AGG_GRID, 256, 0, stream>>>(hf_bf, wgt, rowptr, esort,
                                              biases + L * 128, hpre, part, N_NODES,
                                              L > 0 ? 1 : 0);
    k_bnred<<<256, 256, 0, stream>>>(part, colsum, gammas + L * 128, betas + L * 128,
                                     stats, ctr, AGG_GRID, N_NODES);
  }
  // predictor uses layer-2 BN stats
  k_predm<<<MG_GRID, 256, 0, stream>>>(hpre, stats, Wppack, b_pred, out);
}